// Round 4
// baseline (4301.003 us; speedup 1.0000x reference)
//
#include <hip/hip_runtime.h>
#include <math.h>

#define M_TOTAL 2048
#define N_TOTAL 1024
#define TSEQ    80
#define EMB_D   512
#define VOCAB   50000
#define BK      64

typedef __attribute__((ext_vector_type(8))) short bf16x8;
typedef __attribute__((ext_vector_type(4))) float f32x4;

__device__ __forceinline__ ushort f2bf(float f) {
    union { float f; unsigned u; } v; v.f = f;
    unsigned r = v.u + 0x7FFFu + ((v.u >> 16) & 1u);
    return (ushort)(r >> 16);
}
__device__ __forceinline__ float bf2f(ushort h) {
    union { unsigned u; float f; } v; v.u = ((unsigned)h) << 16;
    return v.f;
}
__device__ __forceinline__ void gload_lds16(const ushort* g, ushort* l) {
    __builtin_amdgcn_global_load_lds(
        (const __attribute__((address_space(1))) void*)g,
        (__attribute__((address_space(3))) void*)l, 16, 0, 0);
}

#define WAIT4() asm volatile("s_waitcnt vmcnt(4)" ::: "memory")
#define WAIT0() asm volatile("s_waitcnt vmcnt(0)" ::: "memory")
#define SBAR()  __builtin_amdgcn_s_barrier()
#define SCHED0() __builtin_amdgcn_sched_barrier(0)

// Fused per-step kernel: one continuous 48-chunk counted-vmcnt pipeline.
//   chunks  0..15 : acc1 += h1prev @ U1^T   (L1)
//   chunks 16..31 : acc2 += h1prev @ W2^T   (L2 part 1)
//   chunks 32..47 : acc2 += h2c   @ U2^T   (L2 part 2)
// Epilogue1: h1[i] = tanh(acc1 + xw[i] + b1) written OVER the xw slab.
// Epilogue2: h2n   = tanh(acc2 + b2).
__global__ __launch_bounds__(256) void fused_step(
    ushort* __restrict__ xw_h1,         // slab i (xw in, h1 out); alias-safe
    const ushort* __restrict__ h1prev,  // slab i-1 or zeros
    const ushort* __restrict__ U1T,
    const float* __restrict__ b1,
    ushort* __restrict__ h2n,
    const ushort* __restrict__ h2c,
    const ushort* __restrict__ W2T,
    const ushort* __restrict__ U2T,
    const float* __restrict__ b2,
    int c0, int c1)                     // [c0,c1): 0..16, 0..48, or 16..48
{
    __shared__ ushort As[3][64 * BK];
    __shared__ ushort Bs[3][64 * BK];
    const int tid = threadIdx.x;
    const int w = tid >> 6, l = tid & 63;
    const int wr = w >> 1, wc = w & 1;
    const int bid = blockIdx.x;
    const int bn0 = (bid & 15) << 6;
    const int bm0 = (bid >> 4) << 6;

    // staging thread-constants (XOR-pre-swizzled source granule)
    const int lr = l >> 3;
    const int se = ((l & 7) ^ lr) << 3;
    const int r0 = w * 16 + lr;
    const int r1 = r0 + 8;
    const int ld0 = (w * 16 + 0) * BK + l * 8;
    const int ld1 = (w * 16 + 8) * BK + l * 8;
    const size_t ga0 = (size_t)(bm0 + r0) * N_TOTAL + se;
    const size_t ga1 = (size_t)(bm0 + r1) * N_TOTAL + se;
    const size_t gb0 = (size_t)(bn0 + r0) * N_TOTAL + se;
    const size_t gb1 = (size_t)(bn0 + r1) * N_TOTAL + se;

    auto stage = [&](int c, int buf) {
        const ushort* A; const ushort* B; int k0;
        if (c < 16)      { A = h1prev; B = U1T; k0 = c << 6; }
        else if (c < 32) { A = h1prev; B = W2T; k0 = (c - 16) << 6; }
        else             { A = h2c;    B = U2T; k0 = (c - 32) << 6; }
        gload_lds16(A + ga0 + k0, &As[buf][ld0]);
        gload_lds16(B + gb0 + k0, &Bs[buf][ld0]);
        gload_lds16(A + ga1 + k0, &As[buf][ld1]);
        gload_lds16(B + gb1 + k0, &Bs[buf][ld1]);
    };

    // LDS read offsets (swizzled), fixed per thread
    int aoff[2][2], boff[2][2];     // [kf][frag]
    #pragma unroll
    for (int kf = 0; kf < 2; ++kf) {
        const int ke = kf * 32 + (l >> 4) * 8;
        #pragma unroll
        for (int f = 0; f < 2; ++f) {
            const int ar = wr * 32 + f * 16 + (l & 15);
            const int br = wc * 32 + f * 16 + (l & 15);
            aoff[kf][f] = ar * BK + (ke ^ ((ar & 7) << 3));
            boff[kf][f] = br * BK + (ke ^ ((br & 7) << 3));
        }
    }

    f32x4 acc1[2][2] = {}, acc2[2][2] = {};

    auto compute = [&](int buf, f32x4 (&acc)[2][2]) {
        #pragma unroll
        for (int kf = 0; kf < 2; ++kf) {
            bf16x8 a[2], b[2];
            a[0] = *(const bf16x8*)&As[buf][aoff[kf][0]];
            a[1] = *(const bf16x8*)&As[buf][aoff[kf][1]];
            b[0] = *(const bf16x8*)&Bs[buf][boff[kf][0]];
            b[1] = *(const bf16x8*)&Bs[buf][boff[kf][1]];
            #pragma unroll
            for (int mf = 0; mf < 2; ++mf)
                #pragma unroll
                for (int nf = 0; nf < 2; ++nf)
                    acc[mf][nf] = __builtin_amdgcn_mfma_f32_16x16x32_bf16(
                        a[mf], b[nf], acc[mf][nf], 0, 0, 0);
        }
    };

    stage(c0, 0);
    stage(c0 + 1, 1);
    for (int c = c0; c < c1; ++c) {
        if (c + 1 < c1) { WAIT4(); } else { WAIT0(); }   // stage(c) landed
        SBAR(); SCHED0();                                 // all waves' stage(c) visible
        if (c + 2 < c1) stage(c + 2, (c - c0 + 2) % 3);   // prefetch 2 ahead
        const int buf = (c - c0) % 3;
        if (c < 16) compute(buf, acc1);
        else        compute(buf, acc2);
    }

    if (c0 == 0) {       // L1 epilogue: read xw, overwrite with h1
        #pragma unroll
        for (int nf = 0; nf < 2; ++nf) {
            const int col = bn0 + wc * 32 + nf * 16 + (l & 15);
            const float bz = b1[col];
            #pragma unroll
            for (int mf = 0; mf < 2; ++mf) {
                const int rb = bm0 + wr * 32 + mf * 16 + (l >> 4) * 4;
                #pragma unroll
                for (int r = 0; r < 4; ++r) {
                    const size_t idx = (size_t)(rb + r) * N_TOTAL + col;
                    const float vv = acc1[mf][nf][r] + bf2f(xw_h1[idx]) + bz;
                    xw_h1[idx] = f2bf(tanhf(vv));
                }
            }
        }
    }
    if (c1 == 48) {      // L2 epilogue
        #pragma unroll
        for (int nf = 0; nf < 2; ++nf) {
            const int col = bn0 + wc * 32 + nf * 16 + (l & 15);
            const float bz = b2[col];
            #pragma unroll
            for (int mf = 0; mf < 2; ++mf) {
                const int rb = bm0 + wr * 32 + mf * 16 + (l >> 4) * 4;
                #pragma unroll
                for (int r = 0; r < 4; ++r) {
                    const float vv = acc2[mf][nf][r] + bz;
                    h2n[(size_t)(rb + r) * N_TOTAL + col] = f2bf(tanhf(vv));
                }
            }
        }
    }
}

// XW1[t*2048+b][n] = embb[tokens[b][t]] @ W1^T, bf16 gather via global_load_lds
__global__ __launch_bounds__(256) void xw1_gemm(
    ushort* __restrict__ outp,          // [163840][1024] bf16
    const ushort* __restrict__ embb,    // [50000][512] bf16
    const int* __restrict__ tok,        // [2048][80]
    const ushort* __restrict__ W1T)     // [1024][512] bf16
{
    __shared__ ushort As[3][64 * BK];
    __shared__ ushort Bs[3][64 * BK];
    const int tid = threadIdx.x;
    const int w = tid >> 6, l = tid & 63;
    const int wr = w >> 1, wc = w & 1;
    const int bid = blockIdx.x;
    const int bn0 = (bid & 15) << 6;
    const int bm0 = (bid >> 4) << 6;

    const int lr = l >> 3;
    const int se = ((l & 7) ^ lr) << 3;
    const int r0 = w * 16 + lr;
    const int r1 = r0 + 8;
    const int ld0 = (w * 16 + 0) * BK + l * 8;
    const int ld1 = (w * 16 + 8) * BK + l * 8;

    const int g0 = bm0 + r0, g1 = bm0 + r1;
    const int tk0 = tok[(g0 & (M_TOTAL - 1)) * TSEQ + (g0 >> 11)];
    const int tk1 = tok[(g1 & (M_TOTAL - 1)) * TSEQ + (g1 >> 11)];
    const size_t ga0 = (size_t)tk0 * EMB_D + se;
    const size_t ga1 = (size_t)tk1 * EMB_D + se;
    const size_t gb0 = (size_t)(bn0 + r0) * EMB_D + se;
    const size_t gb1 = (size_t)(bn0 + r1) * EMB_D + se;

    auto stage = [&](int c, int buf) {
        const int k0 = c << 6;
        gload_lds16(embb + ga0 + k0, &As[buf][ld0]);
        gload_lds16(W1T  + gb0 + k0, &Bs[buf][ld0]);
        gload_lds16(embb + ga1 + k0, &As[buf][ld1]);
        gload_lds16(W1T  + gb1 + k0, &Bs[buf][ld1]);
    };

    int aoff[2][2], boff[2][2];
    #pragma unroll
    for (int kf = 0; kf < 2; ++kf) {
        const int ke = kf * 32 + (l >> 4) * 8;
        #pragma unroll
        for (int f = 0; f < 2; ++f) {
            const int ar = wr * 32 + f * 16 + (l & 15);
            const int br = wc * 32 + f * 16 + (l & 15);
            aoff[kf][f] = ar * BK + (ke ^ ((ar & 7) << 3));
            boff[kf][f] = br * BK + (ke ^ ((br & 7) << 3));
        }
    }

    f32x4 acc[2][2] = {};
    stage(0, 0);
    stage(1, 1);
    const int c1 = EMB_D / BK;          // 8
    for (int c = 0; c < c1; ++c) {
        if (c + 1 < c1) { WAIT4(); } else { WAIT0(); }
        SBAR(); SCHED0();
        if (c + 2 < c1) stage(c + 2, (c + 2) % 3);
        const int buf = c % 3;
        #pragma unroll
        for (int kf = 0; kf < 2; ++kf) {
            bf16x8 a[2], b[2];
            a[0] = *(const bf16x8*)&As[buf][aoff[kf][0]];
            a[1] = *(const bf16x8*)&As[buf][aoff[kf][1]];
            b[0] = *(const bf16x8*)&Bs[buf][boff[kf][0]];
            b[1] = *(const bf16x8*)&Bs[buf][boff[kf][1]];
            #pragma unroll
            for (int mf = 0; mf < 2; ++mf)
                #pragma unroll
                for (int nf = 0; nf < 2; ++nf)
                    acc[mf][nf] = __builtin_amdgcn_mfma_f32_16x16x32_bf16(
                        a[mf], b[nf], acc[mf][nf], 0, 0, 0);
        }
    }

    #pragma unroll
    for (int nf = 0; nf < 2; ++nf) {
        const int col = bn0 + wc * 32 + nf * 16 + (l & 15);
        #pragma unroll
        for (int mf = 0; mf < 2; ++mf) {
            const int rb = bm0 + wr * 32 + mf * 16 + (l >> 4) * 4;
            #pragma unroll
            for (int r = 0; r < 4; ++r)
                outp[(size_t)(rb + r) * N_TOTAL + col] = f2bf(acc[mf][nf][r]);
        }
    }
}

// emb fp32 -> bf16, 8 elems/thread, exact division (50000*512/8/256 = 12500)
__global__ __launch_bounds__(256) void emb_convert(
    ushort* __restrict__ dst, const float* __restrict__ src)
{
    const size_t i = ((size_t)blockIdx.x * 256 + threadIdx.x) * 8;
    const float4 v0 = *(const float4*)(src + i);
    const float4 v1 = *(const float4*)(src + i + 4);
    const unsigned w0 = f2bf(v0.x) | (f2bf(v0.y) << 16);
    const unsigned w1 = f2bf(v0.z) | (f2bf(v0.w) << 16);
    const unsigned w2 = f2bf(v1.x) | (f2bf(v1.y) << 16);
    const unsigned w3 = f2bf(v1.z) | (f2bf(v1.w) << 16);
    *(uint4*)(dst + i) = make_uint4(w0, w1, w2, w3);
}

// W [K][N] fp32 -> WT [N][K] bf16
__global__ __launch_bounds__(256) void transpose_convert(
    ushort* __restrict__ outT, const float* __restrict__ in, int K, int N)
{
    __shared__ float tile[64][65];
    const int tiles_n = N >> 6;
    const int k0 = (blockIdx.x / tiles_n) << 6;
    const int n0 = (blockIdx.x % tiles_n) << 6;
    const int tid = threadIdx.x;
    const int r = tid >> 4, c = (tid & 15) << 2;
    #pragma unroll
    for (int i = 0; i < 4; ++i) {
        const float4 v = *(const float4*)(in + (size_t)(k0 + r + i * 16) * N + n0 + c);
        tile[r + i * 16][c + 0] = v.x;
        tile[r + i * 16][c + 1] = v.y;
        tile[r + i * 16][c + 2] = v.z;
        tile[r + i * 16][c + 3] = v.w;
    }
    __syncthreads();
    const int n = tid >> 2, ks = (tid & 3) << 4;
    unsigned pk[8];
    #pragma unroll
    for (int j = 0; j < 8; ++j) {
        const unsigned lo = f2bf(tile[ks + 2 * j][n]);
        const unsigned hi = f2bf(tile[ks + 2 * j + 1][n]);
        pk[j] = lo | (hi << 16);
    }
    ushort* dst = outT + (size_t)(n0 + n) * K + k0 + ks;
    *(uint4*)(dst + 0) = make_uint4(pk[0], pk[1], pk[2], pk[3]);
    *(uint4*)(dst + 8) = make_uint4(pk[4], pk[5], pk[6], pk[7]);
}

__global__ __launch_bounds__(256) void out_kernel(
    float* __restrict__ out, const ushort* __restrict__ h2,
    const float* __restrict__ Wo, const float* __restrict__ bo)
{
    const int row  = blockIdx.x * 4 + (threadIdx.x >> 6);
    const int lane = threadIdx.x & 63;
    const ushort* hr = h2 + (size_t)row * N_TOTAL;
    float s = 0.f;
    for (int k = lane; k < N_TOTAL; k += 64)
        s += bf2f(hr[k]) * Wo[k];
    #pragma unroll
    for (int off = 32; off; off >>= 1)
        s += __shfl_down(s, off);
    if (lane == 0)
        out[row] = 1.f / (1.f + expf(-(s + bo[0])));
}

extern "C" void kernel_launch(void* const* d_in, const int* in_sizes, int n_in,
                              void* d_out, int out_size, void* d_ws, size_t ws_size,
                              hipStream_t stream) {
    const int*   tokens = (const int*)  d_in[0];
    const float* emb    = (const float*)d_in[1];
    const float* W1     = (const float*)d_in[2];
    const float* U1     = (const float*)d_in[3];
    const float* b1     = (const float*)d_in[4];
    const float* W2     = (const float*)d_in[5];
    const float* U2     = (const float*)d_in[6];
    const float* b2     = (const float*)d_in[7];
    const float* Wo     = (const float*)d_in[8];
    const float* bo     = (const float*)d_in[9];
    float* out = (float*)d_out;

    char* ws = (char*)d_ws;
    const size_t HB   = (size_t)M_TOTAL * N_TOTAL * sizeof(ushort);   // 4 MB
    const size_t SLAB = (size_t)M_TOTAL * N_TOTAL;                    // elems
    ushort* h1zero = (ushort*)(ws);
    ushort* h2a    = (ushort*)(ws + 1 * HB);
    ushort* h2b    = (ushort*)(ws + 2 * HB);
    size_t off = 3 * HB;
    ushort* W1T = (ushort*)(ws + off); off += (size_t)N_TOTAL * EMB_D   * 2;
    ushort* U1T = (ushort*)(ws + off); off += (size_t)N_TOTAL * N_TOTAL * 2;
    ushort* W2T = (ushort*)(ws + off); off += (size_t)N_TOTAL * N_TOTAL * 2;
    ushort* U2T = (ushort*)(ws + off); off += (size_t)N_TOTAL * N_TOTAL * 2;
    ushort* embb = (ushort*)(ws + off); off += (size_t)VOCAB * EMB_D * 2;
    ushort* XW1  = (ushort*)(ws + off);   // 80 slabs x 4 MB = 335.5 MB

    hipMemsetAsync(h1zero, 0, HB, stream);
    hipMemsetAsync(h2a,    0, HB, stream);

    emb_convert<<<dim3(12500), 256, 0, stream>>>(embb, emb);
    transpose_convert<<<dim3((EMB_D  / 64) * (N_TOTAL / 64)), 256, 0, stream>>>(W1T, W1, EMB_D,   N_TOTAL);
    transpose_convert<<<dim3((N_TOTAL / 64) * (N_TOTAL / 64)), 256, 0, stream>>>(U1T, U1, N_TOTAL, N_TOTAL);
    transpose_convert<<<dim3((N_TOTAL / 64) * (N_TOTAL / 64)), 256, 0, stream>>>(W2T, W2, N_TOTAL, N_TOTAL);
    transpose_convert<<<dim3((N_TOTAL / 64) * (N_TOTAL / 64)), 256, 0, stream>>>(U2T, U2, N_TOTAL, N_TOTAL);

    xw1_gemm<<<dim3(16 * (TSEQ * M_TOTAL / 64)), 256, 0, stream>>>(XW1, embb, tokens, W1T);

    ushort* h2c = h2a; ushort* h2n = h2b;
    for (int i = 0; i <= TSEQ; ++i) {
        const int c0 = (i < TSEQ) ? 0 : 16;
        const int c1 = (i >= 1) ? 48 : 16;
        ushort* slab_i  = (i < TSEQ) ? (XW1 + (size_t)i * SLAB) : XW1;  // unused at i=80
        const ushort* h1prev = (i == 0) ? h1zero : (XW1 + (size_t)(i - 1) * SLAB);
        fused_step<<<dim3(512), 256, 0, stream>>>(
            slab_i, h1prev, U1T, b1, h2n, h2c, W2T, U2T, b2, c0, c1);
        if (i >= 1) { ushort* t = h2c; h2c = h2n; h2n = t; }
    }

    out_kernel<<<dim3(M_TOTAL / 4), dim3(256), 0, stream>>>(out, h2c, Wo, bo);
}

// Round 5
// 2924.556 us; speedup vs baseline: 1.4707x; 1.4707x over previous
//
#include <hip/hip_runtime.h>
#include <math.h>

#define M_TOTAL 2048
#define N_TOTAL 1024
#define TSEQ    80
#define EMB_D   512
#define VOCAB   50000
#define BK      64

typedef __attribute__((ext_vector_type(8))) short bf16x8;
typedef __attribute__((ext_vector_type(4))) float f32x4;

__device__ __forceinline__ ushort f2bf(float f) {
    union { float f; unsigned u; } v; v.f = f;
    unsigned r = v.u + 0x7FFFu + ((v.u >> 16) & 1u);
    return (ushort)(r >> 16);
}
__device__ __forceinline__ float bf2f(ushort h) {
    union { unsigned u; float f; } v; v.u = ((unsigned)h) << 16;
    return v.f;
}
__device__ __forceinline__ void gload_lds16(const ushort* g, ushort* l) {
    __builtin_amdgcn_global_load_lds(
        (const __attribute__((address_space(1))) void*)g,
        (__attribute__((address_space(3))) void*)l, 16, 0, 0);
}

#define WAIT4() asm volatile("s_waitcnt vmcnt(4)" ::: "memory")
#define WAIT0() asm volatile("s_waitcnt vmcnt(0)" ::: "memory")
#define VM0()   asm volatile("s_waitcnt vmcnt(0)" ::: "memory")
#define SBAR()  __builtin_amdgcn_s_barrier()
#define SCHED0() __builtin_amdgcn_sched_barrier(0)

// ---------------------------------------------------------------------------
// Fused per-step kernel, 128x64 tiles, 2-phase double-buffered pipeline.
// Grid = 512 blocks: bid&1 == 0 -> layer1 tile, bid&1 == 1 -> layer2 tile.
//   L1: acc = h1prev @ U1T^T            (16 chunks, K=1024)
//   L2: acc = h1prev @ W2T^T + h2c @ U2T^T  (32 chunks, K=2048)
// L1 epilogue: h1[i] = tanh(acc + xw[i] + b1), written OVER the xw slab.
// L2 epilogue: h2n = tanh(acc + b2).
// ---------------------------------------------------------------------------
__global__ __launch_bounds__(256) void fused_step(
    ushort* __restrict__ xw_h1,
    const ushort* __restrict__ h1prev,
    const ushort* __restrict__ U1T, const float* __restrict__ b1,
    ushort* __restrict__ h2n, const ushort* __restrict__ h2c,
    const ushort* __restrict__ W2T, const ushort* __restrict__ U2T,
    const float* __restrict__ b2, int do_l1, int do_l2)
{
    __shared__ ushort As[2][128 * BK];   // 2 x 16 KB
    __shared__ ushort Bs[2][64 * BK];    // 2 x  8 KB
    const int tid = threadIdx.x;
    const int w = tid >> 6, l = tid & 63;
    const int bid = blockIdx.x;
    const int layer = bid & 1;
    const int job = bid >> 1;                 // 0..255
    const int bm0 = (job >> 4) << 7;          // 16 M-tiles of 128
    const int bn0 = (job & 15) << 6;          // 16 N-tiles of 64

    if (layer ? !do_l2 : !do_l1) return;

    // staging constants (XOR-pre-swizzled source granule; both-sides rule)
    const int lr = l >> 3, lg = l & 7;
    const int se = (lg ^ lr) << 3;

    auto stage = [&](const ushort* __restrict__ A, const ushort* __restrict__ B,
                     int k0, int buf) {
        #pragma unroll
        for (int j = 0; j < 4; ++j)          // A: wave w stages rows w*32..+31
            gload_lds16(A + (size_t)(bm0 + w * 32 + j * 8 + lr) * N_TOTAL + k0 + se,
                        &As[buf][(w * 32 + j * 8) * BK + l * 8]);
        #pragma unroll
        for (int j = 0; j < 2; ++j)          // B: wave w stages rows w*16..+15
            gload_lds16(B + (size_t)(bn0 + w * 16 + j * 8 + lr) * N_TOTAL + k0 + se,
                        &Bs[buf][(w * 16 + j * 8) * BK + l * 8]);
    };

    f32x4 acc[2][4] = {};

    auto compute = [&](int buf) {
        #pragma unroll
        for (int kf = 0; kf < 2; ++kf) {
            const int ke = kf * 32 + (l >> 4) * 8;
            bf16x8 a[2], b[4];
            #pragma unroll
            for (int mf = 0; mf < 2; ++mf) {
                const int row = w * 32 + mf * 16 + (l & 15);
                a[mf] = *(const bf16x8*)&As[buf][row * BK + (ke ^ ((row & 7) << 3))];
            }
            #pragma unroll
            for (int nf = 0; nf < 4; ++nf) {
                const int row = nf * 16 + (l & 15);
                b[nf] = *(const bf16x8*)&Bs[buf][row * BK + (ke ^ ((row & 7) << 3))];
            }
            #pragma unroll
            for (int mf = 0; mf < 2; ++mf)
                #pragma unroll
                for (int nf = 0; nf < 4; ++nf)
                    acc[mf][nf] = __builtin_amdgcn_mfma_f32_16x16x32_bf16(
                        a[mf], b[nf], acc[mf][nf], 0, 0, 0);
        }
    };

    if (layer == 0) {
        stage(h1prev, U1T, 0, 0);
        VM0(); __syncthreads();
        int cur = 0;
        #pragma unroll
        for (int c = 0; c < 16; ++c) {
            if (c + 1 < 16) stage(h1prev, U1T, (c + 1) << 6, cur ^ 1);
            compute(cur);
            VM0(); __syncthreads();
            cur ^= 1;
        }
        #pragma unroll
        for (int nf = 0; nf < 4; ++nf) {
            const int col = bn0 + nf * 16 + (l & 15);
            const float bz = b1[col];
            #pragma unroll
            for (int mf = 0; mf < 2; ++mf) {
                const int rb = bm0 + w * 32 + mf * 16 + (l >> 4) * 4;
                #pragma unroll
                for (int r = 0; r < 4; ++r) {
                    const size_t idx = (size_t)(rb + r) * N_TOTAL + col;
                    xw_h1[idx] = f2bf(tanhf(acc[mf][nf][r] + bf2f(xw_h1[idx]) + bz));
                }
            }
        }
    } else {
        stage(h1prev, W2T, 0, 0);
        VM0(); __syncthreads();
        int cur = 0;
        #pragma unroll
        for (int c = 0; c < 16; ++c) {
            if (c + 1 < 16) stage(h1prev, W2T, (c + 1) << 6, cur ^ 1);
            else            stage(h2c,    U2T, 0,            cur ^ 1);
            compute(cur);
            VM0(); __syncthreads();
            cur ^= 1;
        }
        #pragma unroll
        for (int c = 0; c < 16; ++c) {
            if (c + 1 < 16) stage(h2c, U2T, (c + 1) << 6, cur ^ 1);
            compute(cur);
            VM0(); __syncthreads();
            cur ^= 1;
        }
        #pragma unroll
        for (int nf = 0; nf < 4; ++nf) {
            const int col = bn0 + nf * 16 + (l & 15);
            const float bz = b2[col];
            #pragma unroll
            for (int mf = 0; mf < 2; ++mf) {
                const int rb = bm0 + w * 32 + mf * 16 + (l >> 4) * 4;
                #pragma unroll
                for (int r = 0; r < 4; ++r)
                    h2n[(size_t)(rb + r) * N_TOTAL + col] =
                        f2bf(tanhf(acc[mf][nf][r] + bz));
            }
        }
    }
}

// ---------------------------------------------------------------------------
// XW1[t*2048+b][n] = embb[tokens[b][t]] @ W1^T (bf16 gather, counted pipeline)
// ---------------------------------------------------------------------------
__global__ __launch_bounds__(256) void xw1_gemm(
    ushort* __restrict__ outp,          // [163840][1024] bf16
    const ushort* __restrict__ embb,    // [50000][512] bf16
    const int* __restrict__ tok,        // [2048][80]
    const ushort* __restrict__ W1T)     // [1024][512] bf16
{
    __shared__ ushort As[3][64 * BK];
    __shared__ ushort Bs[3][64 * BK];
    const int tid = threadIdx.x;
    const int w = tid >> 6, l = tid & 63;
    const int wr = w >> 1, wc = w & 1;
    const int bid = blockIdx.x;
    const int bn0 = (bid & 15) << 6;
    const int bm0 = (bid >> 4) << 6;

    const int lr = l >> 3;
    const int se = ((l & 7) ^ lr) << 3;
    const int r0 = w * 16 + lr;
    const int r1 = r0 + 8;
    const int ld0 = (w * 16 + 0) * BK + l * 8;
    const int ld1 = (w * 16 + 8) * BK + l * 8;

    const int g0 = bm0 + r0, g1 = bm0 + r1;
    const int tk0 = tok[(g0 & (M_TOTAL - 1)) * TSEQ + (g0 >> 11)];
    const int tk1 = tok[(g1 & (M_TOTAL - 1)) * TSEQ + (g1 >> 11)];
    const size_t ga0 = (size_t)tk0 * EMB_D + se;
    const size_t ga1 = (size_t)tk1 * EMB_D + se;
    const size_t gb0 = (size_t)(bn0 + r0) * EMB_D + se;
    const size_t gb1 = (size_t)(bn0 + r1) * EMB_D + se;

    auto stage = [&](int c, int buf) {
        const int k0 = c << 6;
        gload_lds16(embb + ga0 + k0, &As[buf][ld0]);
        gload_lds16(W1T  + gb0 + k0, &Bs[buf][ld0]);
        gload_lds16(embb + ga1 + k0, &As[buf][ld1]);
        gload_lds16(W1T  + gb1 + k0, &Bs[buf][ld1]);
    };

    int aoff[2][2], boff[2][2];
    #pragma unroll
    for (int kf = 0; kf < 2; ++kf) {
        const int ke = kf * 32 + (l >> 4) * 8;
        #pragma unroll
        for (int f = 0; f < 2; ++f) {
            const int ar = wr * 32 + f * 16 + (l & 15);
            const int br = wc * 32 + f * 16 + (l & 15);
            aoff[kf][f] = ar * BK + (ke ^ ((ar & 7) << 3));
            boff[kf][f] = br * BK + (ke ^ ((br & 7) << 3));
        }
    }

    f32x4 acc[2][2] = {};
    stage(0, 0);
    stage(1, 1);
    const int c1 = EMB_D / BK;          // 8
    for (int c = 0; c < c1; ++c) {
        if (c + 1 < c1) { WAIT4(); } else { WAIT0(); }
        SBAR(); SCHED0();
        if (c + 2 < c1) stage(c + 2, (c + 2) % 3);
        const int buf = c % 3;
        #pragma unroll
        for (int kf = 0; kf < 2; ++kf) {
            bf16x8 a[2], b[2];
            a[0] = *(const bf16x8*)&As[buf][aoff[kf][0]];
            a[1] = *(const bf16x8*)&As[buf][aoff[kf][1]];
            b[0] = *(const bf16x8*)&Bs[buf][boff[kf][0]];
            b[1] = *(const bf16x8*)&Bs[buf][boff[kf][1]];
            #pragma unroll
            for (int mf = 0; mf < 2; ++mf)
                #pragma unroll
                for (int nf = 0; nf < 2; ++nf)
                    acc[mf][nf] = __builtin_amdgcn_mfma_f32_16x16x32_bf16(
                        a[mf], b[nf], acc[mf][nf], 0, 0, 0);
        }
    }

    #pragma unroll
    for (int nf = 0; nf < 2; ++nf) {
        const int col = bn0 + wc * 32 + nf * 16 + (l & 15);
        #pragma unroll
        for (int mf = 0; mf < 2; ++mf) {
            const int rb = bm0 + wr * 32 + mf * 16 + (l >> 4) * 4;
            #pragma unroll
            for (int r = 0; r < 4; ++r)
                outp[(size_t)(rb + r) * N_TOTAL + col] = f2bf(acc[mf][nf][r]);
        }
    }
}

// emb fp32 -> bf16 (50000*512/8/256 = 12500 blocks)
__global__ __launch_bounds__(256) void emb_convert(
    ushort* __restrict__ dst, const float* __restrict__ src)
{
    const size_t i = ((size_t)blockIdx.x * 256 + threadIdx.x) * 8;
    const float4 v0 = *(const float4*)(src + i);
    const float4 v1 = *(const float4*)(src + i + 4);
    const unsigned w0 = f2bf(v0.x) | (f2bf(v0.y) << 16);
    const unsigned w1 = f2bf(v0.z) | (f2bf(v0.w) << 16);
    const unsigned w2 = f2bf(v1.x) | (f2bf(v1.y) << 16);
    const unsigned w3 = f2bf(v1.z) | (f2bf(v1.w) << 16);
    *(uint4*)(dst + i) = make_uint4(w0, w1, w2, w3);
}

// W [K][N] fp32 -> WT [N][K] bf16
__global__ __launch_bounds__(256) void transpose_convert(
    ushort* __restrict__ outT, const float* __restrict__ in, int K, int N)
{
    __shared__ float tile[64][65];
    const int tiles_n = N >> 6;
    const int k0 = (blockIdx.x / tiles_n) << 6;
    const int n0 = (blockIdx.x % tiles_n) << 6;
    const int tid = threadIdx.x;
    const int r = tid >> 4, c = (tid & 15) << 2;
    #pragma unroll
    for (int i = 0; i < 4; ++i) {
        const float4 v = *(const float4*)(in + (size_t)(k0 + r + i * 16) * N + n0 + c);
        tile[r + i * 16][c + 0] = v.x;
        tile[r + i * 16][c + 1] = v.y;
        tile[r + i * 16][c + 2] = v.z;
        tile[r + i * 16][c + 3] = v.w;
    }
    __syncthreads();
    const int n = tid >> 2, ks = (tid & 3) << 4;
    unsigned pk[8];
    #pragma unroll
    for (int j = 0; j < 8; ++j) {
        const unsigned lo = f2bf(tile[ks + 2 * j][n]);
        const unsigned hi = f2bf(tile[ks + 2 * j + 1][n]);
        pk[j] = lo | (hi << 16);
    }
    ushort* dst = outT + (size_t)(n0 + n) * K + k0 + ks;
    *(uint4*)(dst + 0) = make_uint4(pk[0], pk[1], pk[2], pk[3]);
    *(uint4*)(dst + 8) = make_uint4(pk[4], pk[5], pk[6], pk[7]);
}

__global__ __launch_bounds__(256) void out_kernel(
    float* __restrict__ out, const ushort* __restrict__ h2,
    const float* __restrict__ Wo, const float* __restrict__ bo)
{
    const int row  = blockIdx.x * 4 + (threadIdx.x >> 6);
    const int lane = threadIdx.x & 63;
    const ushort* hr = h2 + (size_t)row * N_TOTAL;
    float s = 0.f;
    for (int k = lane; k < N_TOTAL; k += 64)
        s += bf2f(hr[k]) * Wo[k];
    #pragma unroll
    for (int off = 32; off; off >>= 1)
        s += __shfl_down(s, off);
    if (lane == 0)
        out[row] = 1.f / (1.f + expf(-(s + bo[0])));
}

extern "C" void kernel_launch(void* const* d_in, const int* in_sizes, int n_in,
                              void* d_out, int out_size, void* d_ws, size_t ws_size,
                              hipStream_t stream) {
    const int*   tokens = (const int*)  d_in[0];
    const float* emb    = (const float*)d_in[1];
    const float* W1     = (const float*)d_in[2];
    const float* U1     = (const float*)d_in[3];
    const float* b1     = (const float*)d_in[4];
    const float* W2     = (const float*)d_in[5];
    const float* U2     = (const float*)d_in[6];
    const float* b2     = (const float*)d_in[7];
    const float* Wo     = (const float*)d_in[8];
    const float* bo     = (const float*)d_in[9];
    float* out = (float*)d_out;

    char* ws = (char*)d_ws;
    const size_t HB   = (size_t)M_TOTAL * N_TOTAL * sizeof(ushort);   // 4 MB
    const size_t SLAB = (size_t)M_TOTAL * N_TOTAL;                    // elems
    ushort* h1zero = (ushort*)(ws);
    ushort* h2a    = (ushort*)(ws + 1 * HB);
    ushort* h2b    = (ushort*)(ws + 2 * HB);
    size_t off = 3 * HB;
    ushort* W1T = (ushort*)(ws + off); off += (size_t)N_TOTAL * EMB_D   * 2;
    ushort* U1T = (ushort*)(ws + off); off += (size_t)N_TOTAL * N_TOTAL * 2;
    ushort* W2T = (ushort*)(ws + off); off += (size_t)N_TOTAL * N_TOTAL * 2;
    ushort* U2T = (ushort*)(ws + off); off += (size_t)N_TOTAL * N_TOTAL * 2;
    ushort* embb = (ushort*)(ws + off); off += (size_t)VOCAB * EMB_D * 2;
    ushort* XW1  = (ushort*)(ws + off);   // 80 slabs x 4 MB = 335.5 MB

    hipMemsetAsync(h1zero, 0, HB, stream);
    hipMemsetAsync(h2a,    0, HB, stream);

    emb_convert<<<dim3(12500), 256, 0, stream>>>(embb, emb);
    transpose_convert<<<dim3((EMB_D  / 64) * (N_TOTAL / 64)), 256, 0, stream>>>(W1T, W1, EMB_D,   N_TOTAL);
    transpose_convert<<<dim3((N_TOTAL / 64) * (N_TOTAL / 64)), 256, 0, stream>>>(U1T, U1, N_TOTAL, N_TOTAL);
    transpose_convert<<<dim3((N_TOTAL / 64) * (N_TOTAL / 64)), 256, 0, stream>>>(W2T, W2, N_TOTAL, N_TOTAL);
    transpose_convert<<<dim3((N_TOTAL / 64) * (N_TOTAL / 64)), 256, 0, stream>>>(U2T, U2, N_TOTAL, N_TOTAL);

    xw1_gemm<<<dim3(16 * (TSEQ * M_TOTAL / 64)), 256, 0, stream>>>(XW1, embb, tokens, W1T);

    ushort* h2c = h2a; ushort* h2n = h2b;
    for (int i = 0; i <= TSEQ; ++i) {
        const int do_l1 = (i < TSEQ) ? 1 : 0;
        const int do_l2 = (i >= 1) ? 1 : 0;
        ushort* slab_i  = (i < TSEQ) ? (XW1 + (size_t)i * SLAB) : XW1;
        const ushort* h1prev = (i == 0) ? h1zero : (XW1 + (size_t)(i - 1) * SLAB);
        fused_step<<<dim3(512), 256, 0, stream>>>(
            slab_i, h1prev, U1T, b1, h2n, h2c, W2T, U2T, b2, do_l1, do_l2);
        if (i >= 1) { ushort* t = h2c; h2c = h2n; h2n = t; }
    }

    out_kernel<<<dim3(M_TOTAL / 4), dim3(256), 0, stream>>>(out, h2c, Wo, bo);
}